// Round 6
// baseline (708.060 us; speedup 1.0000x reference)
//
#include <hip/hip_runtime.h>
#include <hip/hip_bf16.h>

// Problem constants: n_sents=64, S=512, D=768, E=2000, P=20000, NL=128, H=512, C=3
// Identities exploited:
//   feats@W1 = A1[p1] + A2[p2] + y[p1] - y[p2];  A1=e@W1[0:768], A2=e@W1[768:1536], y=x@W1[1536:]
//   => precompute U = A1 + Y + b1, V = A2 - Y; then h = relu(U[p1] + V[p2])
//   conf = max softmax prob > 0.3 is ALWAYS true (3 classes => max p >= 1/3)
//   3rd iteration's x-update is dead code (loss/logits computed before update)

#define D_DIM 768
#define H_DIM 512
#define NL_DIM 128

// ============ big fused GEMM: [A1|A2|X0] = e_emb @ [W1a|W1b|W_proj] =========
// M=2000, N=1152 (18 segments of 64 cols), K=768.
// ONE WAVE per block, 64x64 tile, 8x8 per thread (0.5 B LDS-read/FLOP),
// double-buffered LDS, register prefetch, direct stores (no atomics).
// Rationale: f32 GEMM is LDS-read-BW capped (~85 B/cy/CU); 8x8 blocking is
// the highest ratio that fits regs; 1-wave blocks make barriers ~free and
// spread LDS demand (~2.25 blocks/CU) to match per-SIMD FMA demand.
#define GTM 64
#define GTN 64
#define GKB 32

__global__ __launch_bounds__(64) void gemm_fused(
    const float* __restrict__ Ag, const float* __restrict__ W1,
    const float* __restrict__ W_proj,
    float* __restrict__ A1, float* __restrict__ A2, float* __restrict__ X0, int M)
{
    __shared__ float As[2][GKB][GTM + 4];   // transposed A-tile; stride 68 (16B-ok)
    __shared__ float Bs[2][GKB][GTN];
    int t = threadIdx.x;                    // 0..63
    int bx = blockIdx.x;                    // 0..17: output-column segment
    int m0 = blockIdx.y * GTM;
    const float* Bt; float* Ct; int ldb, ldc;
    if (bx < 8)       { Bt = W1 + bx * 64;                           ldb = 512; Ct = A1 + bx * 64;        ldc = 512; }
    else if (bx < 16) { Bt = W1 + (size_t)768 * 512 + (bx - 8) * 64; ldb = 512; Ct = A2 + (bx - 8) * 64;  ldc = 512; }
    else              { Bt = W_proj + (bx - 16) * 64;                ldb = 128; Ct = X0 + (bx - 16) * 64; ldc = 128; }

    int tm = (t >> 3) * 8;                  // this thread's 8 rows
    int tn = (t & 7) * 8;                   // this thread's 8 cols
    bool aval = (m0 + t) < M;
    const float* arow = Ag + (size_t)(m0 + t) * D_DIM;

    float acc[8][8] = {};
    float4 pa[8], pb[8];
    const int NT = D_DIM / GKB;             // 24 K-tiles

    // ---- prologue: stage ktile 0 into buffer 0 ----
#pragma unroll
    for (int j = 0; j < 8; ++j)
        pa[j] = aval ? *(const float4*)(arow + j * 4) : make_float4(0.f, 0.f, 0.f, 0.f);
#pragma unroll
    for (int r = 0; r < 8; ++r) {
        int idx = t + 64 * r;
        pb[r] = *(const float4*)(Bt + (size_t)(idx >> 4) * ldb + (idx & 15) * 4);
    }
#pragma unroll
    for (int j = 0; j < 8; ++j) {
        As[0][4 * j + 0][t] = pa[j].x;
        As[0][4 * j + 1][t] = pa[j].y;
        As[0][4 * j + 2][t] = pa[j].z;
        As[0][4 * j + 3][t] = pa[j].w;
    }
#pragma unroll
    for (int r = 0; r < 8; ++r) {
        int idx = t + 64 * r;
        *(float4*)&Bs[0][idx >> 4][(idx & 15) * 4] = pb[r];
    }
    __syncthreads();

    for (int kt = 0; kt < NT; ++kt) {
        int b = kt & 1;
        if (kt + 1 < NT) {
            int k0 = (kt + 1) * GKB;
#pragma unroll
            for (int j = 0; j < 8; ++j)
                pa[j] = aval ? *(const float4*)(arow + k0 + j * 4) : make_float4(0.f, 0.f, 0.f, 0.f);
#pragma unroll
            for (int r = 0; r < 8; ++r) {
                int idx = t + 64 * r;
                pb[r] = *(const float4*)(Bt + (size_t)(k0 + (idx >> 4)) * ldb + (idx & 15) * 4);
            }
        }
#pragma unroll
        for (int k = 0; k < GKB; ++k) {
            float4 a0 = *(const float4*)&As[b][k][tm];
            float4 a1 = *(const float4*)&As[b][k][tm + 4];
            float4 b0 = *(const float4*)&Bs[b][k][tn];
            float4 b1 = *(const float4*)&Bs[b][k][tn + 4];
            float av[8] = {a0.x, a0.y, a0.z, a0.w, a1.x, a1.y, a1.z, a1.w};
            float bv[8] = {b0.x, b0.y, b0.z, b0.w, b1.x, b1.y, b1.z, b1.w};
#pragma unroll
            for (int i = 0; i < 8; ++i)
#pragma unroll
                for (int j = 0; j < 8; ++j)
                    acc[i][j] += av[i] * bv[j];
        }
        if (kt + 1 < NT) {
            int nb = (kt + 1) & 1;
#pragma unroll
            for (int j = 0; j < 8; ++j) {
                As[nb][4 * j + 0][t] = pa[j].x;
                As[nb][4 * j + 1][t] = pa[j].y;
                As[nb][4 * j + 2][t] = pa[j].z;
                As[nb][4 * j + 3][t] = pa[j].w;
            }
#pragma unroll
            for (int r = 0; r < 8; ++r) {
                int idx = t + 64 * r;
                *(float4*)&Bs[nb][idx >> 4][(idx & 15) * 4] = pb[r];
            }
        }
        __syncthreads();
    }
    // ---- epilogue: direct stores ----
#pragma unroll
    for (int i = 0; i < 8; ++i) {
        int row = m0 + tm + i;
        if (row < M) {
            float* cp = Ct + (size_t)row * ldc + tn;
            *(float4*)cp       = make_float4(acc[i][0], acc[i][1], acc[i][2], acc[i][3]);
            *(float4*)(cp + 4) = make_float4(acc[i][4], acc[i][5], acc[i][6], acc[i][7]);
        }
    }
}

// ============ small-GEMM machinery (64x64, 4x4/thread, 256 thr) =============
#define KB 32
#define TM 64
#define TN 64

struct Smem {
    float As[KB][TM + 4];
    float Bs[KB][TN];
};

__device__ __forceinline__ void tile_compute(Smem& sm, float acc[4][4], int tm, int tn)
{
#pragma unroll
    for (int k = 0; k < KB; ++k) {
        float4 a = *(const float4*)&sm.As[k][tm * 4];
        float4 b = *(const float4*)&sm.Bs[k][tn * 4];
        acc[0][0] += a.x * b.x; acc[0][1] += a.x * b.y; acc[0][2] += a.x * b.z; acc[0][3] += a.x * b.w;
        acc[1][0] += a.y * b.x; acc[1][1] += a.y * b.y; acc[1][2] += a.y * b.z; acc[1][3] += a.y * b.w;
        acc[2][0] += a.z * b.x; acc[2][1] += a.z * b.y; acc[2][2] += a.z * b.z; acc[2][3] += a.z * b.w;
        acc[3][0] += a.w * b.x; acc[3][1] += a.w * b.y; acc[3][2] += a.w * b.z; acc[3][3] += a.w * b.w;
    }
}

__device__ __forceinline__ void stage_b(Smem& sm, const float* __restrict__ Bt,
                                        int k0, int ldb, int t)
{
#pragma unroll
    for (int r = 0; r < 2; ++r) {
        int row = (t >> 4) + 16 * r;
        int c4 = (t & 15) * 4;
        *(float4*)&sm.Bs[row][c4] = *(const float4*)(Bt + (size_t)(k0 + row) * ldb + c4);
    }
}

// ---- y = x@W1[1536:], epilogue: U = A1+y+b1, V = A2-y; + zero scatter bufs -
__global__ __launch_bounds__(256) void gemm_y_uv(
    const float* __restrict__ x, const float* __restrict__ W1k,
    const float* __restrict__ A1, const float* __restrict__ A2,
    const float* __restrict__ b1,
    float* __restrict__ U, float* __restrict__ V,
    float4* __restrict__ zbase, int zn4, int M)
{
    __shared__ Smem sm;
    int t = threadIdx.x;
    int n0 = blockIdx.x * TN;
    int m0 = blockIdx.y * TM;
    int tm = t >> 4, tn = t & 15;
    int ar = t >> 3, c4 = (t & 7) * 4;
    float acc[4][4] = {};
    for (int k0 = 0; k0 < NL_DIM; k0 += KB) {
#pragma unroll
        for (int r = 0; r < 2; ++r) {
            int row = m0 + ar + 32 * r;
            float4 av = make_float4(0.f, 0.f, 0.f, 0.f);
            if (row < M)
                av = *(const float4*)(x + (size_t)row * NL_DIM + k0 + c4);
            sm.As[c4 + 0][ar + 32 * r] = av.x;
            sm.As[c4 + 1][ar + 32 * r] = av.y;
            sm.As[c4 + 2][ar + 32 * r] = av.z;
            sm.As[c4 + 3][ar + 32 * r] = av.w;
        }
        stage_b(sm, W1k + n0, k0, H_DIM, t);
        __syncthreads();
        tile_compute(sm, acc, tm, tn);
        __syncthreads();
    }
    float4 b1v = *(const float4*)(b1 + n0 + tn * 4);
#pragma unroll
    for (int i = 0; i < 4; ++i) {
        int row = m0 + tm * 4 + i;
        if (row < M) {
            size_t off = (size_t)row * H_DIM + n0 + tn * 4;
            float4 a1v = *(const float4*)(A1 + off);
            float4 a2v = *(const float4*)(A2 + off);
            float4 u, v;
            u.x = acc[i][0] + a1v.x + b1v.x;  v.x = a2v.x - acc[i][0];
            u.y = acc[i][1] + a1v.y + b1v.y;  v.y = a2v.y - acc[i][1];
            u.z = acc[i][2] + a1v.z + b1v.z;  v.z = a2v.z - acc[i][2];
            u.w = acc[i][3] + a1v.w + b1v.w;  v.w = a2v.w - acc[i][3];
            *(float4*)(U + off) = u;
            *(float4*)(V + off) = v;
        }
    }
    // fused zeroing of s_intra|s_inter|c_intra|c_inter (contiguous region)
    int nb = gridDim.x * gridDim.y;                       // 256 blocks
    int bid = blockIdx.y * gridDim.x + blockIdx.x;
    int chunk = (zn4 + nb - 1) / nb;
    for (int i = t; i < chunk; i += 256) {
        int idx = bid * chunk + i;
        if (idx < zn4) zbase[idx] = make_float4(0.f, 0.f, 0.f, 0.f);
    }
}

// ---- xnext = relu(x@W_self + aggI@W_intra + aggE@W_inter), agg fused ------
__global__ __launch_bounds__(256) void gemm_update3(
    const float* __restrict__ x,
    const float* __restrict__ s_intra, const float* __restrict__ s_inter,
    const float* __restrict__ c_intra, const float* __restrict__ c_inter,
    const float* __restrict__ Ws, const float* __restrict__ Wi, const float* __restrict__ We,
    float* __restrict__ xn, int M)
{
    __shared__ Smem sm;
    int t = threadIdx.x;
    int n0 = blockIdx.x * TN;
    int m0 = blockIdx.y * TM;
    int tm = t >> 4, tn = t & 15;
    int ar = t >> 3, c4 = (t & 7) * 4;
    float acc[4][4] = {};
    for (int ph = 0; ph < 3; ++ph) {
        const float* Bt = (ph == 0 ? Ws : ph == 1 ? Wi : We) + n0;
        for (int k0 = 0; k0 < NL_DIM; k0 += KB) {
#pragma unroll
            for (int r = 0; r < 2; ++r) {
                int row = m0 + ar + 32 * r;
                float4 av = make_float4(0.f, 0.f, 0.f, 0.f);
                if (row < M) {
                    size_t off = (size_t)row * NL_DIM + k0 + c4;
                    if (ph == 0) {
                        av = *(const float4*)(x + off);
                    } else if (ph == 1) {
                        float4 s = *(const float4*)(s_intra + off);
                        float4 xv = *(const float4*)(x + off);
                        float sc = 0.7f / (c_intra[row] + 1.0f);
                        av = make_float4((s.x + xv.x) * sc, (s.y + xv.y) * sc,
                                         (s.z + xv.z) * sc, (s.w + xv.w) * sc);
                    } else {
                        float4 s = *(const float4*)(s_inter + off);
                        float sc = 0.3f / fmaxf(c_inter[row], 1.0f);
                        av = make_float4(s.x * sc, s.y * sc, s.z * sc, s.w * sc);
                    }
                }
                sm.As[c4 + 0][ar + 32 * r] = av.x;
                sm.As[c4 + 1][ar + 32 * r] = av.y;
                sm.As[c4 + 2][ar + 32 * r] = av.z;
                sm.As[c4 + 3][ar + 32 * r] = av.w;
            }
            stage_b(sm, Bt, k0, NL_DIM, t);
            __syncthreads();
            tile_compute(sm, acc, tm, tn);
            __syncthreads();
        }
    }
#pragma unroll
    for (int i = 0; i < 4; ++i) {
        int row = m0 + tm * 4 + i;
        if (row < M)
            *(float4*)(xn + (size_t)row * NL_DIM + n0 + tn * 4) =
                make_float4(fmaxf(acc[i][0], 0.f), fmaxf(acc[i][1], 0.f),
                            fmaxf(acc[i][2], 0.f), fmaxf(acc[i][3], 0.f));
    }
}

// ---- extract events: e_emb[e] = mean of masked token span -----------------
__global__ __launch_bounds__(192) void extract_kernel(
    const float* __restrict__ sent_emb, const int* __restrict__ es,
    const int* __restrict__ st, const int* __restrict__ el,
    float* __restrict__ e_emb)
{
    int e = blockIdx.x;
    int t = threadIdx.x;               // one float4 each (768 floats)
    int s = es[e];
    int start = st[e];
    int len = el[e] + 1;               // in [1,8]; start+7 <= 510, no clip needed
    const float* base = sent_emb + ((size_t)s * 512 + start) * D_DIM;
    float4 a = make_float4(0.f, 0.f, 0.f, 0.f);
    for (int k = 0; k < len; ++k) {
        float4 v = ((const float4*)(base + (size_t)k * D_DIM))[t];
        a.x += v.x; a.y += v.y; a.z += v.z; a.w += v.w;
    }
    float inv = 1.0f / (float)len;
    ((float4*)(e_emb + (size_t)e * D_DIM))[t] =
        make_float4(a.x * inv, a.y * inv, a.z * inv, a.w * inv);
}

// ---- fused per-pair kernel: 4 waves/block, 4 pairs/wave, batched loads ----
__global__ __launch_bounds__(256) void pair_kernel(
    const float* __restrict__ U, const float* __restrict__ V,
    const float* __restrict__ X, const float* __restrict__ W2,
    const float* __restrict__ b2,
    const int* __restrict__ pair1, const int* __restrict__ pair2,
    const int* __restrict__ rel, const int* __restrict__ tgt,
    float* s_intra, float* s_inter, float* c_intra, float* c_inter,
    float* __restrict__ ce_out, float* logits_out, int P, int do_scatter)
{
    __shared__ float ce_sh[4];
    int t = threadIdx.x;
    int wave = t >> 6;
    int lane = t & 63;
    int base = lane * 8;               // this lane's 8 dims of 512
    float w2f[24];
    {
        const float4* w2p = (const float4*)(W2 + (size_t)base * 3);
#pragma unroll
        for (int q = 0; q < 6; ++q) *(float4*)&w2f[q * 4] = w2p[q];
    }
    float b20 = b2[0], b21 = b2[1], b22 = b2[2];
    int p0 = (blockIdx.x * 4 + wave) * 4;

    int pi1[4], pi2[4];
#pragma unroll
    for (int q = 0; q < 4; ++q) {
        int p = min(p0 + q, P - 1);
        pi1[q] = pair1[p];
        pi2[q] = pair2[p];
    }
    float uf[4][8], vf[4][8];
#pragma unroll
    for (int q = 0; q < 4; ++q) {
        const float4* up = (const float4*)(U + (size_t)pi1[q] * H_DIM + base);
        const float4* vp = (const float4*)(V + (size_t)pi2[q] * H_DIM + base);
        *(float4*)&uf[q][0] = up[0]; *(float4*)&uf[q][4] = up[1];
        *(float4*)&vf[q][0] = vp[0]; *(float4*)&vf[q][4] = vp[1];
    }

    float ce = 0.f;
#pragma unroll
    for (int q = 0; q < 4; ++q) {
        int p = p0 + q;
        if (p >= P) break;
        float l0 = 0.f, l1 = 0.f, l2 = 0.f;
#pragma unroll
        for (int i = 0; i < 8; ++i) {
            float h = fmaxf(uf[q][i] + vf[q][i], 0.f);
            l0 += h * w2f[i * 3 + 0];
            l1 += h * w2f[i * 3 + 1];
            l2 += h * w2f[i * 3 + 2];
        }
#pragma unroll
        for (int off = 32; off > 0; off >>= 1) {
            l0 += __shfl_xor(l0, off);
            l1 += __shfl_xor(l1, off);
            l2 += __shfl_xor(l2, off);
        }
        l0 += b20; l1 += b21; l2 += b22;
        float m = fmaxf(l0, fmaxf(l1, l2));
        float lse = m + logf(expf(l0 - m) + expf(l1 - m) + expf(l2 - m));
        int tg = tgt[p];
        float lt = (tg == 0) ? l0 : ((tg == 1) ? l1 : l2);
        ce += lse - lt;
        if (logits_out && lane == 0) {
            logits_out[(size_t)p * 3 + 0] = l0;
            logits_out[(size_t)p * 3 + 1] = l1;
            logits_out[(size_t)p * 3 + 2] = l2;
        }
        if (do_scatter) {
            int argm = 0; float mx = l0;
            if (l1 > mx) { mx = l1; argm = 1; }
            if (l2 > mx) { mx = l2; argm = 2; }
            if (argm != 0) {
                int r = rel[p];
                int src = (argm == 1) ? pi1[q] : pi2[q];
                int dst = (argm == 1) ? pi2[q] : pi1[q];
                float* sacc = (r == 0) ? s_intra : s_inter;
                float* cacc = (r == 0) ? c_intra : c_inter;
                const float* xs = X + (size_t)src * NL_DIM;
                float* sd = sacc + (size_t)dst * NL_DIM;
                atomicAdd(&sd[lane], xs[lane]);
                atomicAdd(&sd[lane + 64], xs[lane + 64]);
                if (lane == 0) atomicAdd(&cacc[dst], 1.0f);
            }
        }
    }
    if (lane == 0) ce_sh[wave] = ce;
    __syncthreads();
    if (t == 0) ce_out[blockIdx.x] = ce_sh[0] + ce_sh[1] + ce_sh[2] + ce_sh[3];
}

// ---- final deterministic loss reduce --------------------------------------
__global__ __launch_bounds__(256) void loss_kernel(
    const float* __restrict__ ce, int nblk, int P, float* __restrict__ out)
{
    int t = threadIdx.x;
    float acc = 0.f;
    for (int it = 0; it < 3; ++it) {
        float w = 1.0f / ((float)P * (float)(it + 1));
        for (int i = t; i < nblk; i += 256)
            acc += ce[(size_t)it * nblk + i] * w;
    }
    __shared__ float red[256];
    red[t] = acc;
    __syncthreads();
    for (int s = 128; s > 0; s >>= 1) {
        if (t < s) red[t] += red[t + s];
        __syncthreads();
    }
    if (t == 0) out[0] = red[0];
}

extern "C" void kernel_launch(void* const* d_in, const int* in_sizes, int n_in,
                              void* d_out, int out_size, void* d_ws, size_t ws_size,
                              hipStream_t stream)
{
    const float* sent_emb  = (const float*)d_in[0];
    const float* W_proj    = (const float*)d_in[1];
    const float* W1        = (const float*)d_in[2];
    const float* b1        = (const float*)d_in[3];
    const float* W2        = (const float*)d_in[4];
    const float* b2        = (const float*)d_in[5];
    const float* W_self    = (const float*)d_in[6];
    const float* W_intra   = (const float*)d_in[7];
    const float* W_inter   = (const float*)d_in[8];
    const int* event_sent  = (const int*)d_in[9];
    const int* event_start = (const int*)d_in[10];
    const int* event_len   = (const int*)d_in[11];
    const int* pair1       = (const int*)d_in[12];
    const int* pair2       = (const int*)d_in[13];
    const int* rel_type    = (const int*)d_in[14];
    const int* target      = (const int*)d_in[15];

    int E = in_sizes[9];    // 2000
    int P = in_sizes[12];   // 20000
    float* out = (float*)d_out;
    float* ws  = (float*)d_ws;

    // workspace layout (16B-aligned offsets). U aliases dead e_emb region.
    size_t o = 0;
    float* e_emb   = ws + o; o += (size_t)E * D_DIM;    // 2000x768 (dead after gemm_fused)
    float* A1      = ws + o; o += (size_t)E * H_DIM;
    float* A2      = ws + o; o += (size_t)E * H_DIM;
    float* X0      = ws + o; o += (size_t)E * NL_DIM;
    float* V       = ws + o; o += (size_t)E * H_DIM;
    float* X1      = ws + o; o += (size_t)E * NL_DIM;
    float* s_intra = ws + o; o += (size_t)E * NL_DIM;   // | contiguous zero region
    float* s_inter = ws + o; o += (size_t)E * NL_DIM;   // |
    float* c_intra = ws + o; o += (size_t)E;            // |
    float* c_inter = ws + o; o += (size_t)E;            // |
    int NBLK = (P + 15) / 16;                           // 1250
    float* ceb     = ws + o; o += (size_t)3 * NBLK;
    float* U       = e_emb;                             // alias: E*512 <= E*768

    // 1) event embeddings
    extract_kernel<<<E, 192, 0, stream>>>(sent_emb, event_sent, event_start, event_len, e_emb);

    // 2) big fused GEMM (direct write)
    dim3 gF(18, (E + GTM - 1) / GTM);                   // 18 x 32 = 576 one-wave blocks
    gemm_fused<<<gF, 64, 0, stream>>>(e_emb, W1, W_proj, A1, A2, X0, E);

    const float* W1k = W1 + (size_t)2 * D_DIM * H_DIM;  // rows 1536..1663
    dim3 gY(H_DIM / TN, (E + TM - 1) / TM);             // 8 x 32
    dim3 gU(NL_DIM / TN, (E + TM - 1) / TM);            // 2 x 32
    float* xcur = X0;
    float* xnext = X1;
    int zn4 = (E * NL_DIM * 2 + E * 2) / 4;             // s_intra..c_inter in float4s
    for (int it = 0; it < 3; ++it) {
        int last = (it == 2);
        gemm_y_uv<<<gY, 256, 0, stream>>>(xcur, W1k, A1, A2, b1, U, V,
                                          (float4*)s_intra, zn4, E);
        pair_kernel<<<NBLK, 256, 0, stream>>>(U, V, xcur, W2, b2,
                                              pair1, pair2, rel_type, target,
                                              s_intra, s_inter, c_intra, c_inter,
                                              ceb + (size_t)it * NBLK,
                                              last ? (out + 1) : nullptr, P, !last);
        if (!last) {
            gemm_update3<<<gU, 256, 0, stream>>>(xcur, s_intra, s_inter, c_intra, c_inter,
                                                 W_self, W_intra, W_inter, xnext, E);
            float* tmp = xcur; xcur = xnext; xnext = tmp;
        }
    }
    loss_kernel<<<1, 256, 0, stream>>>(ceb, NBLK, P, out);
}

// Round 8
// 590.031 us; speedup vs baseline: 1.2000x; 1.2000x over previous
//
#include <hip/hip_runtime.h>
#include <hip/hip_bf16.h>

// Problem constants: n_sents=64, S=512, D=768, E=2000, P=20000, NL=128, H=512, C=3
// Identities exploited:
//   feats@W1 = A1[p1] + A2[p2] + y[p1] - y[p2];  A1=e@W1[0:768], A2=e@W1[768:1536], y=x@W1[1536:]
//   => precompute U = A1 + Y + b1, V = A2 - Y; then h = relu(U[p1] + V[p2])
//   conf = max softmax prob > 0.3 is ALWAYS true (3 classes => max p >= 1/3)
//   3rd iteration's x-update is dead code (loss/logits computed before update)

#define D_DIM 768
#define H_DIM 512
#define NL_DIM 128

// ============ big fused GEMM: [A1|A2|X0] = e_emb @ [W1a|W1b|W_proj] =========
// M=2000, N=1152 (18 segments of 64 cols), K=768.
// ONE WAVE per block, 64x64 tile, 8x8/thread. 576 blocks <= 1024 SIMD slots:
// every block runs on its own SIMD concurrently; single-wave barriers ~free.
// B staged via global_load_lds (0 VGPRs, natural [k][n] layout is linear);
// A staged via 8 float4 regs + transpose ds_writes (2-way bank alias = free).
// VGPR budget: 64 acc + 32 A-stage + 16 frag + addr ~= 150 (no spill; R6's
// 256-VGPR spill came from the extra 16-float4 prefetch array).
#define GTM 64
#define GTN 64
#define GKB 32
#define NKT (D_DIM / GKB)   // 24

__device__ __forceinline__ void stage_b_async(float (*bs)[GTN], const float* Bt,
                                              int ldb, int k0, int t)
{
#if defined(__has_builtin) && __has_builtin(__builtin_amdgcn_global_load_lds)
    // lane t writes bs[i*4 + t/16][(t%16)*4 .. +3]  <- Bt[(k0+i*4+t/16)*ldb + (t%16)*4]
    const float* lsrc = Bt + (size_t)(k0 + (t >> 4)) * ldb + (t & 15) * 4;
#pragma unroll
    for (int i = 0; i < 8; ++i) {
        __builtin_amdgcn_global_load_lds(
            (const __attribute__((address_space(1))) void*)(lsrc + (size_t)4 * i * ldb),
            (__attribute__((address_space(3))) void*)&bs[i * 4][0], 16, 0, 0);
    }
#else
#pragma unroll
    for (int i = 0; i < 8; ++i) {
        float4 v = *(const float4*)(Bt + (size_t)(k0 + i * 4 + (t >> 4)) * ldb + (t & 15) * 4);
        *(float4*)&bs[i * 4 + (t >> 4)][(t & 15) * 4] = v;
    }
#endif
}

__global__ __launch_bounds__(64) void gemm_fused(
    const float* __restrict__ Ag, const float* __restrict__ W1,
    const float* __restrict__ W_proj,
    float* __restrict__ A1, float* __restrict__ A2, float* __restrict__ X0, int M)
{
    __shared__ float As[2][GKB][GTM];   // transposed A: [k][m]
    __shared__ float Bs[2][GKB][GTN];   // natural B: [k][n] (global_load_lds linear)
    int t = threadIdx.x;                // 0..63
    int bx = blockIdx.x;                // 0..17: output-column segment
    int m0 = blockIdx.y * GTM;
    const float* Bt; float* Ct; int ldb, ldc;
    if (bx < 8)       { Bt = W1 + bx * 64;                           ldb = 512; Ct = A1 + bx * 64;        ldc = 512; }
    else if (bx < 16) { Bt = W1 + (size_t)768 * 512 + (bx - 8) * 64; ldb = 512; Ct = A2 + (bx - 8) * 64;  ldc = 512; }
    else              { Bt = W_proj + (bx - 16) * 64;                ldb = 128; Ct = X0 + (bx - 16) * 64; ldc = 128; }

    bool aval = (m0 + t) < M;
    const float* arow = Ag + (size_t)(m0 + t) * D_DIM;   // lane's own A row
    int tm8 = (t >> 3) * 8;
    int tn8 = (t & 7) * 8;

    float acc[8][8] = {};
    float4 pa[8];

    // ---- prologue: stage ktile 0 ----
    stage_b_async(Bs[0], Bt, ldb, 0, t);
#pragma unroll
    for (int j = 0; j < 8; ++j)
        pa[j] = aval ? *(const float4*)(arow + j * 4) : make_float4(0.f, 0.f, 0.f, 0.f);
#pragma unroll
    for (int j = 0; j < 8; ++j) {
        As[0][4 * j + 0][t] = pa[j].x;
        As[0][4 * j + 1][t] = pa[j].y;
        As[0][4 * j + 2][t] = pa[j].z;
        As[0][4 * j + 3][t] = pa[j].w;
    }
    __syncthreads();   // drains vmcnt (global_load_lds) + lgkm (ds_write)

    for (int kt = 0; kt < NKT; ++kt) {
        int cur = kt & 1, nxt = cur ^ 1;
        if (kt + 1 < NKT) {
            int k0 = (kt + 1) * GKB;
            stage_b_async(Bs[nxt], Bt, ldb, k0, t);      // async, no regs
#pragma unroll
            for (int j = 0; j < 8; ++j)
                pa[j] = aval ? *(const float4*)(arow + k0 + j * 4) : make_float4(0.f, 0.f, 0.f, 0.f);
        }
#pragma unroll
        for (int k = 0; k < GKB; ++k) {
            float4 alo = *(const float4*)&As[cur][k][tm8];
            float4 ahi = *(const float4*)&As[cur][k][tm8 + 4];
            float4 blo = *(const float4*)&Bs[cur][k][tn8];
            float4 bhi = *(const float4*)&Bs[cur][k][tn8 + 4];
            float av[8] = {alo.x, alo.y, alo.z, alo.w, ahi.x, ahi.y, ahi.z, ahi.w};
            float bv[8] = {blo.x, blo.y, blo.z, blo.w, bhi.x, bhi.y, bhi.z, bhi.w};
#pragma unroll
            for (int i = 0; i < 8; ++i)
#pragma unroll
                for (int j = 0; j < 8; ++j)
                    acc[i][j] += av[i] * bv[j];
        }
        if (kt + 1 < NKT) {
#pragma unroll
            for (int j = 0; j < 8; ++j) {
                As[nxt][4 * j + 0][t] = pa[j].x;
                As[nxt][4 * j + 1][t] = pa[j].y;
                As[nxt][4 * j + 2][t] = pa[j].z;
                As[nxt][4 * j + 3][t] = pa[j].w;
            }
        }
        __syncthreads();
    }
    // ---- epilogue: direct stores ----
#pragma unroll
    for (int i = 0; i < 8; ++i) {
        int row = m0 + tm8 + i;
        if (row < M) {
            float* cp = Ct + (size_t)row * ldc + tn8;
            *(float4*)cp       = make_float4(acc[i][0], acc[i][1], acc[i][2], acc[i][3]);
            *(float4*)(cp + 4) = make_float4(acc[i][4], acc[i][5], acc[i][6], acc[i][7]);
        }
    }
}

// ============ small-GEMM machinery (64x64, 4x4/thread, 256 thr) =============
#define KB 32
#define TM 64
#define TN 64

struct Smem {
    float As[KB][TM + 4];
    float Bs[KB][TN];
};

__device__ __forceinline__ void tile_compute(Smem& sm, float acc[4][4], int tm, int tn)
{
#pragma unroll
    for (int k = 0; k < KB; ++k) {
        float4 a = *(const float4*)&sm.As[k][tm * 4];
        float4 b = *(const float4*)&sm.Bs[k][tn * 4];
        acc[0][0] += a.x * b.x; acc[0][1] += a.x * b.y; acc[0][2] += a.x * b.z; acc[0][3] += a.x * b.w;
        acc[1][0] += a.y * b.x; acc[1][1] += a.y * b.y; acc[1][2] += a.y * b.z; acc[1][3] += a.y * b.w;
        acc[2][0] += a.z * b.x; acc[2][1] += a.z * b.y; acc[2][2] += a.z * b.z; acc[2][3] += a.z * b.w;
        acc[3][0] += a.w * b.x; acc[3][1] += a.w * b.y; acc[3][2] += a.w * b.z; acc[3][3] += a.w * b.w;
    }
}

__device__ __forceinline__ void stage_b(Smem& sm, const float* __restrict__ Bt,
                                        int k0, int ldb, int t)
{
#pragma unroll
    for (int r = 0; r < 2; ++r) {
        int row = (t >> 4) + 16 * r;
        int c4 = (t & 15) * 4;
        *(float4*)&sm.Bs[row][c4] = *(const float4*)(Bt + (size_t)(k0 + row) * ldb + c4);
    }
}

// ---- y = x@W1[1536:], epilogue: U = A1+y+b1, V = A2-y; + zero scatter bufs -
__global__ __launch_bounds__(256) void gemm_y_uv(
    const float* __restrict__ x, const float* __restrict__ W1k,
    const float* __restrict__ A1, const float* __restrict__ A2,
    const float* __restrict__ b1,
    float* __restrict__ U, float* __restrict__ V,
    float4* __restrict__ zbase, int zn4, int M)
{
    __shared__ Smem sm;
    int t = threadIdx.x;
    int n0 = blockIdx.x * TN;
    int m0 = blockIdx.y * TM;
    int tm = t >> 4, tn = t & 15;
    int ar = t >> 3, c4 = (t & 7) * 4;
    float acc[4][4] = {};
    for (int k0 = 0; k0 < NL_DIM; k0 += KB) {
#pragma unroll
        for (int r = 0; r < 2; ++r) {
            int row = m0 + ar + 32 * r;
            float4 av = make_float4(0.f, 0.f, 0.f, 0.f);
            if (row < M)
                av = *(const float4*)(x + (size_t)row * NL_DIM + k0 + c4);
            sm.As[c4 + 0][ar + 32 * r] = av.x;
            sm.As[c4 + 1][ar + 32 * r] = av.y;
            sm.As[c4 + 2][ar + 32 * r] = av.z;
            sm.As[c4 + 3][ar + 32 * r] = av.w;
        }
        stage_b(sm, W1k + n0, k0, H_DIM, t);
        __syncthreads();
        tile_compute(sm, acc, tm, tn);
        __syncthreads();
    }
    float4 b1v = *(const float4*)(b1 + n0 + tn * 4);
#pragma unroll
    for (int i = 0; i < 4; ++i) {
        int row = m0 + tm * 4 + i;
        if (row < M) {
            size_t off = (size_t)row * H_DIM + n0 + tn * 4;
            float4 a1v = *(const float4*)(A1 + off);
            float4 a2v = *(const float4*)(A2 + off);
            float4 u, v;
            u.x = acc[i][0] + a1v.x + b1v.x;  v.x = a2v.x - acc[i][0];
            u.y = acc[i][1] + a1v.y + b1v.y;  v.y = a2v.y - acc[i][1];
            u.z = acc[i][2] + a1v.z + b1v.z;  v.z = a2v.z - acc[i][2];
            u.w = acc[i][3] + a1v.w + b1v.w;  v.w = a2v.w - acc[i][3];
            *(float4*)(U + off) = u;
            *(float4*)(V + off) = v;
        }
    }
    // fused zeroing of s_intra|s_inter|c_intra|c_inter (contiguous region)
    int nb = gridDim.x * gridDim.y;
    int bid = blockIdx.y * gridDim.x + blockIdx.x;
    int chunk = (zn4 + nb - 1) / nb;
    for (int i = t; i < chunk; i += 256) {
        int idx = bid * chunk + i;
        if (idx < zn4) zbase[idx] = make_float4(0.f, 0.f, 0.f, 0.f);
    }
}

// ---- xnext = relu(x@W_self + aggI@W_intra + aggE@W_inter), agg fused ------
__global__ __launch_bounds__(256) void gemm_update3(
    const float* __restrict__ x,
    const float* __restrict__ s_intra, const float* __restrict__ s_inter,
    const float* __restrict__ c_intra, const float* __restrict__ c_inter,
    const float* __restrict__ Ws, const float* __restrict__ Wi, const float* __restrict__ We,
    float* __restrict__ xn, int M)
{
    __shared__ Smem sm;
    int t = threadIdx.x;
    int n0 = blockIdx.x * TN;
    int m0 = blockIdx.y * TM;
    int tm = t >> 4, tn = t & 15;
    int ar = t >> 3, c4 = (t & 7) * 4;
    float acc[4][4] = {};
    for (int ph = 0; ph < 3; ++ph) {
        const float* Bt = (ph == 0 ? Ws : ph == 1 ? Wi : We) + n0;
        for (int k0 = 0; k0 < NL_DIM; k0 += KB) {
#pragma unroll
            for (int r = 0; r < 2; ++r) {
                int row = m0 + ar + 32 * r;
                float4 av = make_float4(0.f, 0.f, 0.f, 0.f);
                if (row < M) {
                    size_t off = (size_t)row * NL_DIM + k0 + c4;
                    if (ph == 0) {
                        av = *(const float4*)(x + off);
                    } else if (ph == 1) {
                        float4 s = *(const float4*)(s_intra + off);
                        float4 xv = *(const float4*)(x + off);
                        float sc = 0.7f / (c_intra[row] + 1.0f);
                        av = make_float4((s.x + xv.x) * sc, (s.y + xv.y) * sc,
                                         (s.z + xv.z) * sc, (s.w + xv.w) * sc);
                    } else {
                        float4 s = *(const float4*)(s_inter + off);
                        float sc = 0.3f / fmaxf(c_inter[row], 1.0f);
                        av = make_float4(s.x * sc, s.y * sc, s.z * sc, s.w * sc);
                    }
                }
                sm.As[c4 + 0][ar + 32 * r] = av.x;
                sm.As[c4 + 1][ar + 32 * r] = av.y;
                sm.As[c4 + 2][ar + 32 * r] = av.z;
                sm.As[c4 + 3][ar + 32 * r] = av.w;
            }
            stage_b(sm, Bt, k0, NL_DIM, t);
            __syncthreads();
            tile_compute(sm, acc, tm, tn);
            __syncthreads();
        }
    }
#pragma unroll
    for (int i = 0; i < 4; ++i) {
        int row = m0 + tm * 4 + i;
        if (row < M)
            *(float4*)(xn + (size_t)row * NL_DIM + n0 + tn * 4) =
                make_float4(fmaxf(acc[i][0], 0.f), fmaxf(acc[i][1], 0.f),
                            fmaxf(acc[i][2], 0.f), fmaxf(acc[i][3], 0.f));
    }
}

// ---- extract events: e_emb[e] = mean of masked token span -----------------
__global__ __launch_bounds__(192) void extract_kernel(
    const float* __restrict__ sent_emb, const int* __restrict__ es,
    const int* __restrict__ st, const int* __restrict__ el,
    float* __restrict__ e_emb)
{
    int e = blockIdx.x;
    int t = threadIdx.x;               // one float4 each (768 floats)
    int s = es[e];
    int start = st[e];
    int len = el[e] + 1;               // in [1,8]; start+7 <= 510, no clip needed
    const float* base = sent_emb + ((size_t)s * 512 + start) * D_DIM;
    float4 a = make_float4(0.f, 0.f, 0.f, 0.f);
    for (int k = 0; k < len; ++k) {
        float4 v = ((const float4*)(base + (size_t)k * D_DIM))[t];
        a.x += v.x; a.y += v.y; a.z += v.z; a.w += v.w;
    }
    float inv = 1.0f / (float)len;
    ((float4*)(e_emb + (size_t)e * D_DIM))[t] =
        make_float4(a.x * inv, a.y * inv, a.z * inv, a.w * inv);
}

// ---- fused per-pair kernel: 4 waves/block, 4 pairs/wave, batched loads ----
__global__ __launch_bounds__(256) void pair_kernel(
    const float* __restrict__ U, const float* __restrict__ V,
    const float* __restrict__ X, const float* __restrict__ W2,
    const float* __restrict__ b2,
    const int* __restrict__ pair1, const int* __restrict__ pair2,
    const int* __restrict__ rel, const int* __restrict__ tgt,
    float* s_intra, float* s_inter, float* c_intra, float* c_inter,
    float* __restrict__ ce_out, float* logits_out, int P, int do_scatter)
{
    __shared__ float ce_sh[4];
    int t = threadIdx.x;
    int wave = t >> 6;
    int lane = t & 63;
    int base = lane * 8;               // this lane's 8 dims of 512
    float w2f[24];
    {
        const float4* w2p = (const float4*)(W2 + (size_t)base * 3);
#pragma unroll
        for (int q = 0; q < 6; ++q) *(float4*)&w2f[q * 4] = w2p[q];
    }
    float b20 = b2[0], b21 = b2[1], b22 = b2[2];
    int p0 = (blockIdx.x * 4 + wave) * 4;

    int pi1[4], pi2[4];
#pragma unroll
    for (int q = 0; q < 4; ++q) {
        int p = min(p0 + q, P - 1);
        pi1[q] = pair1[p];
        pi2[q] = pair2[p];
    }
    float uf[4][8], vf[4][8];
#pragma unroll
    for (int q = 0; q < 4; ++q) {
        const float4* up = (const float4*)(U + (size_t)pi1[q] * H_DIM + base);
        const float4* vp = (const float4*)(V + (size_t)pi2[q] * H_DIM + base);
        *(float4*)&uf[q][0] = up[0]; *(float4*)&uf[q][4] = up[1];
        *(float4*)&vf[q][0] = vp[0]; *(float4*)&vf[q][4] = vp[1];
    }

    float ce = 0.f;
#pragma unroll
    for (int q = 0; q < 4; ++q) {
        int p = p0 + q;
        if (p >= P) break;
        float l0 = 0.f, l1 = 0.f, l2 = 0.f;
#pragma unroll
        for (int i = 0; i < 8; ++i) {
            float h = fmaxf(uf[q][i] + vf[q][i], 0.f);
            l0 += h * w2f[i * 3 + 0];
            l1 += h * w2f[i * 3 + 1];
            l2 += h * w2f[i * 3 + 2];
        }
#pragma unroll
        for (int off = 32; off > 0; off >>= 1) {
            l0 += __shfl_xor(l0, off);
            l1 += __shfl_xor(l1, off);
            l2 += __shfl_xor(l2, off);
        }
        l0 += b20; l1 += b21; l2 += b22;
        float m = fmaxf(l0, fmaxf(l1, l2));
        float lse = m + logf(expf(l0 - m) + expf(l1 - m) + expf(l2 - m));
        int tg = tgt[p];
        float lt = (tg == 0) ? l0 : ((tg == 1) ? l1 : l2);
        ce += lse - lt;
        if (logits_out && lane == 0) {
            logits_out[(size_t)p * 3 + 0] = l0;
            logits_out[(size_t)p * 3 + 1] = l1;
            logits_out[(size_t)p * 3 + 2] = l2;
        }
        if (do_scatter) {
            int argm = 0; float mx = l0;
            if (l1 > mx) { mx = l1; argm = 1; }
            if (l2 > mx) { mx = l2; argm = 2; }
            if (argm != 0) {
                int r = rel[p];
                int src = (argm == 1) ? pi1[q] : pi2[q];
                int dst = (argm == 1) ? pi2[q] : pi1[q];
                float* sacc = (r == 0) ? s_intra : s_inter;
                float* cacc = (r == 0) ? c_intra : c_inter;
                const float* xs = X + (size_t)src * NL_DIM;
                float* sd = sacc + (size_t)dst * NL_DIM;
                atomicAdd(&sd[lane], xs[lane]);
                atomicAdd(&sd[lane + 64], xs[lane + 64]);
                if (lane == 0) atomicAdd(&cacc[dst], 1.0f);
            }
        }
    }
    if (lane == 0) ce_sh[wave] = ce;
    __syncthreads();
    if (t == 0) ce_out[blockIdx.x] = ce_sh[0] + ce_sh[1] + ce_sh[2] + ce_sh[3];
}

// ---- final deterministic loss reduce --------------------------------------
__global__ __launch_bounds__(256) void loss_kernel(
    const float* __restrict__ ce, int nblk, int P, float* __restrict__ out)
{
    int t = threadIdx.x;
    float acc = 0.f;
    for (int it = 0; it < 3; ++it) {
        float w = 1.0f / ((float)P * (float)(it + 1));
        for (int i = t; i < nblk; i += 256)
            acc += ce[(size_t)it * nblk + i] * w;
    }
    __shared__ float red[256];
    red[t] = acc;
    __syncthreads();
    for (int s = 128; s > 0; s >>= 1) {
        if (t < s) red[t] += red[t + s];
        __syncthreads();
    }
    if (t == 0) out[0] = red[0];
}

extern "C" void kernel_launch(void* const* d_in, const int* in_sizes, int n_in,
                              void* d_out, int out_size, void* d_ws, size_t ws_size,
                              hipStream_t stream)
{
    const float* sent_emb  = (const float*)d_in[0];
    const float* W_proj    = (const float*)d_in[1];
    const float* W1        = (const float*)d_in[2];
    const float* b1        = (const float*)d_in[3];
    const float* W2        = (const float*)d_in[4];
    const float* b2        = (const float*)d_in[5];
    const float* W_self    = (const float*)d_in[6];
    const float* W_intra   = (const float*)d_in[7];
    const float* W_inter   = (const float*)d_in[8];
    const int* event_sent  = (const int*)d_in[9];
    const int* event_start = (const int*)d_in[10];
    const int* event_len   = (const int*)d_in[11];
    const int* pair1       = (const int*)d_in[12];
    const int* pair2       = (const int*)d_in[13];
    const int* rel_type    = (const int*)d_in[14];
    const int* target      = (const int*)d_in[15];

    int E = in_sizes[9];    // 2000
    int P = in_sizes[12];   // 20000
    float* out = (float*)d_out;
    float* ws  = (float*)d_ws;

    // workspace layout (16B-aligned offsets). U aliases dead e_emb region.
    size_t o = 0;
    float* e_emb   = ws + o; o += (size_t)E * D_DIM;    // 2000x768 (dead after gemm_fused)
    float* A1      = ws + o; o += (size_t)E * H_DIM;
    float* A2      = ws + o; o += (size_t)E * H_DIM;
    float* X0      = ws + o; o += (size_t)E * NL_DIM;
    float* V       = ws + o; o += (size_t)E * H_DIM;
    float* X1      = ws + o; o += (size_t)E * NL_DIM;
    float* s_intra = ws + o; o += (size_t)E * NL_DIM;   // | contiguous zero region
    float* s_inter = ws + o; o += (size_t)E * NL_DIM;   // |
    float* c_intra = ws + o; o += (size_t)E;            // |
    float* c_inter = ws + o; o += (size_t)E;            // |
    int NBLK = (P + 15) / 16;                           // 1250
    float* ceb     = ws + o; o += (size_t)3 * NBLK;
    float* U       = e_emb;                             // alias: E*512 <= E*768

    // 1) event embeddings
    extract_kernel<<<E, 192, 0, stream>>>(sent_emb, event_sent, event_start, event_len, e_emb);

    // 2) big fused GEMM (one-wave blocks, direct write)
    dim3 gF(18, (E + GTM - 1) / GTM);                   // 18 x 32 = 576 one-wave blocks
    gemm_fused<<<gF, 64, 0, stream>>>(e_emb, W1, W_proj, A1, A2, X0, E);

    const float* W1k = W1 + (size_t)2 * D_DIM * H_DIM;  // rows 1536..1663
    dim3 gY(H_DIM / TN, (E + TM - 1) / TM);             // 8 x 32
    dim3 gU(NL_DIM / TN, (E + TM - 1) / TM);            // 2 x 32
    float* xcur = X0;
    float* xnext = X1;
    int zn4 = (E * NL_DIM * 2 + E * 2) / 4;             // s_intra..c_inter in float4s
    for (int it = 0; it < 3; ++it) {
        int last = (it == 2);
        gemm_y_uv<<<gY, 256, 0, stream>>>(xcur, W1k, A1, A2, b1, U, V,
                                          (float4*)s_intra, zn4, E);
        pair_kernel<<<NBLK, 256, 0, stream>>>(U, V, xcur, W2, b2,
                                              pair1, pair2, rel_type, target,
                                              s_intra, s_inter, c_intra, c_inter,
                                              ceb + (size_t)it * NBLK,
                                              last ? (out + 1) : nullptr, P, !last);
        if (!last) {
            gemm_update3<<<gU, 256, 0, stream>>>(xcur, s_intra, s_inter, c_intra, c_inter,
                                                 W_self, W_intra, W_inter, xnext, E);
            float* tmp = xcur; xcur = xnext; xnext = tmp;
        }
    }
    loss_kernel<<<1, 256, 0, stream>>>(ceb, NBLK, P, out);
}

// Round 9
// 468.839 us; speedup vs baseline: 1.5102x; 1.2585x over previous
//
#include <hip/hip_runtime.h>
#include <hip/hip_bf16.h>

// Problem constants: n_sents=64, S=512, D=768, E=2000, P=20000, NL=128, H=512, C=3
// Identities exploited:
//   feats@W1 = A1[p1] + A2[p2] + y[p1] - y[p2];  A1=e@W1[0:768], A2=e@W1[768:1536], y=x@W1[1536:]
//   => precompute U = A1 + Y + b1, V = A2 - Y; then h = relu(U[p1] + V[p2])
//   conf = max softmax prob > 0.3 is ALWAYS true (3 classes => max p >= 1/3)
//   3rd iteration's x-update is dead code (loss/logits computed before update)

#define D_DIM 768
#define H_DIM 512
#define NL_DIM 128

// ============ big fused GEMM: [A1|A2|X0] = e_emb @ [W1a|W1b|W_proj] =========
// M=2000, N=1152 (18 segments of 64 cols), K=768. One wave/block, 64x64 tile,
// 8x8/thread. BOTH A and B staged via global_load_lds => ZERO staging VGPRs
// (R6/R8 spilled at 256 VGPR from reg-staged A + unroll lookahead).
// A LDS layout [64 rows][32 k] with XOR col-chunk swizzle (both-sides):
//   LDS[row][c] = Global[row][c ^ ((row>>3)&7)]   (c = float4 chunk 0..7)
// staged by pre-swizzling the per-lane GLOBAL address (dest stays linear,
// as global_load_lds requires); read back with the same XOR -> per-read
// instruction the 8 row-groups hit 8 distinct bank quads = conflict-free.
// #pragma unroll 2 on the k-chunk loop caps scheduler lookahead (~120 VGPR).
#define GTM 64
#define GTN 64
#define GKB 32
#define NKT (D_DIM / GKB)   // 24

#define HAVE_GLL (defined(__has_builtin) && __has_builtin(__builtin_amdgcn_global_load_lds))

__device__ __forceinline__ void stage_a_async(float* as, const float* Ag,
                                              int m0, int k0, int t)
{
    int row = t >> 3;            // 0..7 within each 8-row group
    int cp  = t & 7;             // col-chunk position in LDS
#if HAVE_GLL
#pragma unroll
    for (int q = 0; q < 8; ++q) {
        const float* src = Ag + (size_t)(m0 + q * 8 + row) * D_DIM + k0 + ((cp ^ q) * 4);
        __builtin_amdgcn_global_load_lds(
            (const __attribute__((address_space(1))) void*)src,
            (__attribute__((address_space(3))) void*)(as + q * 256), 16, 0, 0);
    }
#else
#pragma unroll
    for (int q = 0; q < 8; ++q) {
        float4 v = *(const float4*)(Ag + (size_t)(m0 + q * 8 + row) * D_DIM + k0 + ((cp ^ q) * 4));
        *(float4*)&as[q * 256 + t * 4] = v;
    }
#endif
}

__device__ __forceinline__ void stage_b_async(float* bs, const float* Bt,
                                              int ldb, int k0, int t)
{
#if HAVE_GLL
    const float* lsrc = Bt + (size_t)(k0 + (t >> 4)) * ldb + (t & 15) * 4;
#pragma unroll
    for (int i = 0; i < 8; ++i)
        __builtin_amdgcn_global_load_lds(
            (const __attribute__((address_space(1))) void*)(lsrc + (size_t)4 * i * ldb),
            (__attribute__((address_space(3))) void*)(bs + i * 256), 16, 0, 0);
#else
#pragma unroll
    for (int i = 0; i < 8; ++i) {
        float4 v = *(const float4*)(Bt + (size_t)(k0 + i * 4 + (t >> 4)) * ldb + (t & 15) * 4);
        *(float4*)&bs[i * 256 + t * 4] = v;
    }
#endif
}

__global__ __launch_bounds__(64) void gemm_fused(
    const float* __restrict__ Ag, const float* __restrict__ W1,
    const float* __restrict__ W_proj,
    float* __restrict__ A1, float* __restrict__ A2, float* __restrict__ X0, int M)
{
    __shared__ float As[2][GKB * GTM];  // [row][k] swizzled, 8KB each
    __shared__ float Bs[2][GKB * GTN];  // [k][n] natural, 8KB each
    int t = threadIdx.x;                // 0..63
    int bx = blockIdx.x;                // 0..17: output-column segment
    int m0 = blockIdx.y * GTM;
    const float* Bt; float* Ct; int ldb, ldc;
    if (bx < 8)       { Bt = W1 + bx * 64;                           ldb = 512; Ct = A1 + bx * 64;        ldc = 512; }
    else if (bx < 16) { Bt = W1 + (size_t)768 * 512 + (bx - 8) * 64; ldb = 512; Ct = A2 + (bx - 8) * 64;  ldc = 512; }
    else              { Bt = W_proj + (bx - 16) * 64;                ldb = 128; Ct = X0 + (bx - 16) * 64; ldc = 128; }
    // NOTE: A rows m0..m0+63 may exceed M for the last blockIdx.y; those rows
    // read garbage from adjacent ws regions (valid memory) and are not stored.

    int rsw = t >> 3;                   // row-group = swizzle key for reads
    int tm8 = (t >> 3) * 8;
    int tn8 = (t & 7) * 8;

    float acc[8][8] = {};

    stage_a_async(As[0], Ag, m0, 0, t);
    stage_b_async(Bs[0], Bt, ldb, 0, t);
    __syncthreads();                    // drains vmcnt for buf 0

    for (int kt = 0; kt < NKT; ++kt) {
        int cur = kt & 1, nxt = cur ^ 1;
        if (kt + 1 < NKT) {
            stage_a_async(As[nxt], Ag, m0, (kt + 1) * GKB, t);
            stage_b_async(Bs[nxt], Bt, ldb, (kt + 1) * GKB, t);
        }
        const float* as = As[cur];
        const float* bs = Bs[cur];
#pragma unroll 2
        for (int kc = 0; kc < 8; ++kc) {
            int csw = ((kc ^ rsw) & 7) * 4;     // swizzled col chunk (floats)
            float4 a[8];
#pragma unroll
            for (int i = 0; i < 8; ++i)
                a[i] = *(const float4*)&as[(tm8 + i) * 32 + csw];
#pragma unroll
            for (int kk = 0; kk < 4; ++kk) {
                float4 bl = *(const float4*)&bs[(kc * 4 + kk) * 64 + tn8];
                float4 bh = *(const float4*)&bs[(kc * 4 + kk) * 64 + tn8 + 4];
#pragma unroll
                for (int i = 0; i < 8; ++i) {
                    float aw = (kk == 0) ? a[i].x : (kk == 1) ? a[i].y
                             : (kk == 2) ? a[i].z : a[i].w;
                    acc[i][0] += aw * bl.x; acc[i][1] += aw * bl.y;
                    acc[i][2] += aw * bl.z; acc[i][3] += aw * bl.w;
                    acc[i][4] += aw * bh.x; acc[i][5] += aw * bh.y;
                    acc[i][6] += aw * bh.z; acc[i][7] += aw * bh.w;
                }
            }
        }
        __syncthreads();
    }
    // ---- epilogue: direct stores ----
#pragma unroll
    for (int i = 0; i < 8; ++i) {
        int row = m0 + tm8 + i;
        if (row < M) {
            float* cp = Ct + (size_t)row * ldc + tn8;
            *(float4*)cp       = make_float4(acc[i][0], acc[i][1], acc[i][2], acc[i][3]);
            *(float4*)(cp + 4) = make_float4(acc[i][4], acc[i][5], acc[i][6], acc[i][7]);
        }
    }
}

// ============ small-GEMM machinery (64x64, 4x4/thread, 256 thr) =============
#define KB 32
#define TM 64
#define TN 64

struct Smem {
    float As[KB][TM + 4];
    float Bs[KB][TN];
};

__device__ __forceinline__ void tile_compute(Smem& sm, float acc[4][4], int tm, int tn)
{
#pragma unroll
    for (int k = 0; k < KB; ++k) {
        float4 a = *(const float4*)&sm.As[k][tm * 4];
        float4 b = *(const float4*)&sm.Bs[k][tn * 4];
        acc[0][0] += a.x * b.x; acc[0][1] += a.x * b.y; acc[0][2] += a.x * b.z; acc[0][3] += a.x * b.w;
        acc[1][0] += a.y * b.x; acc[1][1] += a.y * b.y; acc[1][2] += a.y * b.z; acc[1][3] += a.y * b.w;
        acc[2][0] += a.z * b.x; acc[2][1] += a.z * b.y; acc[2][2] += a.z * b.z; acc[2][3] += a.z * b.w;
        acc[3][0] += a.w * b.x; acc[3][1] += a.w * b.y; acc[3][2] += a.w * b.z; acc[3][3] += a.w * b.w;
    }
}

__device__ __forceinline__ void stage_b(Smem& sm, const float* __restrict__ Bt,
                                        int k0, int ldb, int t)
{
#pragma unroll
    for (int r = 0; r < 2; ++r) {
        int row = (t >> 4) + 16 * r;
        int c4 = (t & 15) * 4;
        *(float4*)&sm.Bs[row][c4] = *(const float4*)(Bt + (size_t)(k0 + row) * ldb + c4);
    }
}

// ---- y = x@W1[1536:], epilogue: U = A1+y+b1, V = A2-y; + zero scatter bufs -
__global__ __launch_bounds__(256) void gemm_y_uv(
    const float* __restrict__ x, const float* __restrict__ W1k,
    const float* __restrict__ A1, const float* __restrict__ A2,
    const float* __restrict__ b1,
    float* __restrict__ U, float* __restrict__ V,
    float4* __restrict__ zbase, int zn4, int M)
{
    __shared__ Smem sm;
    int t = threadIdx.x;
    int n0 = blockIdx.x * TN;
    int m0 = blockIdx.y * TM;
    int tm = t >> 4, tn = t & 15;
    int ar = t >> 3, c4 = (t & 7) * 4;
    float acc[4][4] = {};
    for (int k0 = 0; k0 < NL_DIM; k0 += KB) {
#pragma unroll
        for (int r = 0; r < 2; ++r) {
            int row = m0 + ar + 32 * r;
            float4 av = make_float4(0.f, 0.f, 0.f, 0.f);
            if (row < M)
                av = *(const float4*)(x + (size_t)row * NL_DIM + k0 + c4);
            sm.As[c4 + 0][ar + 32 * r] = av.x;
            sm.As[c4 + 1][ar + 32 * r] = av.y;
            sm.As[c4 + 2][ar + 32 * r] = av.z;
            sm.As[c4 + 3][ar + 32 * r] = av.w;
        }
        stage_b(sm, W1k + n0, k0, H_DIM, t);
        __syncthreads();
        tile_compute(sm, acc, tm, tn);
        __syncthreads();
    }
    float4 b1v = *(const float4*)(b1 + n0 + tn * 4);
#pragma unroll
    for (int i = 0; i < 4; ++i) {
        int row = m0 + tm * 4 + i;
        if (row < M) {
            size_t off = (size_t)row * H_DIM + n0 + tn * 4;
            float4 a1v = *(const float4*)(A1 + off);
            float4 a2v = *(const float4*)(A2 + off);
            float4 u, v;
            u.x = acc[i][0] + a1v.x + b1v.x;  v.x = a2v.x - acc[i][0];
            u.y = acc[i][1] + a1v.y + b1v.y;  v.y = a2v.y - acc[i][1];
            u.z = acc[i][2] + a1v.z + b1v.z;  v.z = a2v.z - acc[i][2];
            u.w = acc[i][3] + a1v.w + b1v.w;  v.w = a2v.w - acc[i][3];
            *(float4*)(U + off) = u;
            *(float4*)(V + off) = v;
        }
    }
    // fused zeroing of s_intra|s_inter|c_intra|c_inter (contiguous region)
    int nb = gridDim.x * gridDim.y;
    int bid = blockIdx.y * gridDim.x + blockIdx.x;
    int chunk = (zn4 + nb - 1) / nb;
    for (int i = t; i < chunk; i += 256) {
        int idx = bid * chunk + i;
        if (idx < zn4) zbase[idx] = make_float4(0.f, 0.f, 0.f, 0.f);
    }
}

// ---- xnext = relu(x@W_self + aggI@W_intra + aggE@W_inter), agg fused ------
__global__ __launch_bounds__(256) void gemm_update3(
    const float* __restrict__ x,
    const float* __restrict__ s_intra, const float* __restrict__ s_inter,
    const float* __restrict__ c_intra, const float* __restrict__ c_inter,
    const float* __restrict__ Ws, const float* __restrict__ Wi, const float* __restrict__ We,
    float* __restrict__ xn, int M)
{
    __shared__ Smem sm;
    int t = threadIdx.x;
    int n0 = blockIdx.x * TN;
    int m0 = blockIdx.y * TM;
    int tm = t >> 4, tn = t & 15;
    int ar = t >> 3, c4 = (t & 7) * 4;
    float acc[4][4] = {};
    for (int ph = 0; ph < 3; ++ph) {
        const float* Bt = (ph == 0 ? Ws : ph == 1 ? Wi : We) + n0;
        for (int k0 = 0; k0 < NL_DIM; k0 += KB) {
#pragma unroll
            for (int r = 0; r < 2; ++r) {
                int row = m0 + ar + 32 * r;
                float4 av = make_float4(0.f, 0.f, 0.f, 0.f);
                if (row < M) {
                    size_t off = (size_t)row * NL_DIM + k0 + c4;
                    if (ph == 0) {
                        av = *(const float4*)(x + off);
                    } else if (ph == 1) {
                        float4 s = *(const float4*)(s_intra + off);
                        float4 xv = *(const float4*)(x + off);
                        float sc = 0.7f / (c_intra[row] + 1.0f);
                        av = make_float4((s.x + xv.x) * sc, (s.y + xv.y) * sc,
                                         (s.z + xv.z) * sc, (s.w + xv.w) * sc);
                    } else {
                        float4 s = *(const float4*)(s_inter + off);
                        float sc = 0.3f / fmaxf(c_inter[row], 1.0f);
                        av = make_float4(s.x * sc, s.y * sc, s.z * sc, s.w * sc);
                    }
                }
                sm.As[c4 + 0][ar + 32 * r] = av.x;
                sm.As[c4 + 1][ar + 32 * r] = av.y;
                sm.As[c4 + 2][ar + 32 * r] = av.z;
                sm.As[c4 + 3][ar + 32 * r] = av.w;
            }
            stage_b(sm, Bt, k0, NL_DIM, t);
            __syncthreads();
            tile_compute(sm, acc, tm, tn);
            __syncthreads();
        }
    }
#pragma unroll
    for (int i = 0; i < 4; ++i) {
        int row = m0 + tm * 4 + i;
        if (row < M)
            *(float4*)(xn + (size_t)row * NL_DIM + n0 + tn * 4) =
                make_float4(fmaxf(acc[i][0], 0.f), fmaxf(acc[i][1], 0.f),
                            fmaxf(acc[i][2], 0.f), fmaxf(acc[i][3], 0.f));
    }
}

// ---- extract events: e_emb[e] = mean of masked token span -----------------
__global__ __launch_bounds__(192) void extract_kernel(
    const float* __restrict__ sent_emb, const int* __restrict__ es,
    const int* __restrict__ st, const int* __restrict__ el,
    float* __restrict__ e_emb)
{
    int e = blockIdx.x;
    int t = threadIdx.x;               // one float4 each (768 floats)
    int s = es[e];
    int start = st[e];
    int len = el[e] + 1;               // in [1,8]; start+7 <= 510, no clip needed
    const float* base = sent_emb + ((size_t)s * 512 + start) * D_DIM;
    float4 a = make_float4(0.f, 0.f, 0.f, 0.f);
    for (int k = 0; k < len; ++k) {
        float4 v = ((const float4*)(base + (size_t)k * D_DIM))[t];
        a.x += v.x; a.y += v.y; a.z += v.z; a.w += v.w;
    }
    float inv = 1.0f / (float)len;
    ((float4*)(e_emb + (size_t)e * D_DIM))[t] =
        make_float4(a.x * inv, a.y * inv, a.z * inv, a.w * inv);
}

// ---- fused per-pair kernel: 4 waves/block, 4 pairs/wave, batched loads ----
__global__ __launch_bounds__(256) void pair_kernel(
    const float* __restrict__ U, const float* __restrict__ V,
    const float* __restrict__ X, const float* __restrict__ W2,
    const float* __restrict__ b2,
    const int* __restrict__ pair1, const int* __restrict__ pair2,
    const int* __restrict__ rel, const int* __restrict__ tgt,
    float* s_intra, float* s_inter, float* c_intra, float* c_inter,
    float* __restrict__ ce_out, float* logits_out, int P, int do_scatter)
{
    __shared__ float ce_sh[4];
    int t = threadIdx.x;
    int wave = t >> 6;
    int lane = t & 63;
    int base = lane * 8;               // this lane's 8 dims of 512
    float w2f[24];
    {
        const float4* w2p = (const float4*)(W2 + (size_t)base * 3);
#pragma unroll
        for (int q = 0; q < 6; ++q) *(float4*)&w2f[q * 4] = w2p[q];
    }
    float b20 = b2[0], b21 = b2[1], b22 = b2[2];
    int p0 = (blockIdx.x * 4 + wave) * 4;

    int pi1[4], pi2[4];
#pragma unroll
    for (int q = 0; q < 4; ++q) {
        int p = min(p0 + q, P - 1);
        pi1[q] = pair1[p];
        pi2[q] = pair2[p];
    }
    float uf[4][8], vf[4][8];
#pragma unroll
    for (int q = 0; q < 4; ++q) {
        const float4* up = (const float4*)(U + (size_t)pi1[q] * H_DIM + base);
        const float4* vp = (const float4*)(V + (size_t)pi2[q] * H_DIM + base);
        *(float4*)&uf[q][0] = up[0]; *(float4*)&uf[q][4] = up[1];
        *(float4*)&vf[q][0] = vp[0]; *(float4*)&vf[q][4] = vp[1];
    }

    float ce = 0.f;
#pragma unroll
    for (int q = 0; q < 4; ++q) {
        int p = p0 + q;
        if (p >= P) break;
        float l0 = 0.f, l1 = 0.f, l2 = 0.f;
#pragma unroll
        for (int i = 0; i < 8; ++i) {
            float h = fmaxf(uf[q][i] + vf[q][i], 0.f);
            l0 += h * w2f[i * 3 + 0];
            l1 += h * w2f[i * 3 + 1];
            l2 += h * w2f[i * 3 + 2];
        }
#pragma unroll
        for (int off = 32; off > 0; off >>= 1) {
            l0 += __shfl_xor(l0, off);
            l1 += __shfl_xor(l1, off);
            l2 += __shfl_xor(l2, off);
        }
        l0 += b20; l1 += b21; l2 += b22;
        float m = fmaxf(l0, fmaxf(l1, l2));
        float lse = m + logf(expf(l0 - m) + expf(l1 - m) + expf(l2 - m));
        int tg = tgt[p];
        float lt = (tg == 0) ? l0 : ((tg == 1) ? l1 : l2);
        ce += lse - lt;
        if (logits_out && lane == 0) {
            logits_out[(size_t)p * 3 + 0] = l0;
            logits_out[(size_t)p * 3 + 1] = l1;
            logits_out[(size_t)p * 3 + 2] = l2;
        }
        if (do_scatter) {
            int argm = 0; float mx = l0;
            if (l1 > mx) { mx = l1; argm = 1; }
            if (l2 > mx) { mx = l2; argm = 2; }
            if (argm != 0) {
                int r = rel[p];
                int src = (argm == 1) ? pi1[q] : pi2[q];
                int dst = (argm == 1) ? pi2[q] : pi1[q];
                float* sacc = (r == 0) ? s_intra : s_inter;
                float* cacc = (r == 0) ? c_intra : c_inter;
                const float* xs = X + (size_t)src * NL_DIM;
                float* sd = sacc + (size_t)dst * NL_DIM;
                atomicAdd(&sd[lane], xs[lane]);
                atomicAdd(&sd[lane + 64], xs[lane + 64]);
                if (lane == 0) atomicAdd(&cacc[dst], 1.0f);
            }
        }
    }
    if (lane == 0) ce_sh[wave] = ce;
    __syncthreads();
    if (t == 0) ce_out[blockIdx.x] = ce_sh[0] + ce_sh[1] + ce_sh[2] + ce_sh[3];
}

// ---- final deterministic loss reduce --------------------------------------
__global__ __launch_bounds__(256) void loss_kernel(
    const float* __restrict__ ce, int nblk, int P, float* __restrict__ out)
{
    int t = threadIdx.x;
    float acc = 0.f;
    for (int it = 0; it < 3; ++it) {
        float w = 1.0f / ((float)P * (float)(it + 1));
        for (int i = t; i < nblk; i += 256)
            acc += ce[(size_t)it * nblk + i] * w;
    }
    __shared__ float red[256];
    red[t] = acc;
    __syncthreads();
    for (int s = 128; s > 0; s >>= 1) {
        if (t < s) red[t] += red[t + s];
        __syncthreads();
    }
    if (t == 0) out[0] = red[0];
}

extern "C" void kernel_launch(void* const* d_in, const int* in_sizes, int n_in,
                              void* d_out, int out_size, void* d_ws, size_t ws_size,
                              hipStream_t stream)
{
    const float* sent_emb  = (const float*)d_in[0];
    const float* W_proj    = (const float*)d_in[1];
    const float* W1        = (const float*)d_in[2];
    const float* b1        = (const float*)d_in[3];
    const float* W2        = (const float*)d_in[4];
    const float* b2        = (const float*)d_in[5];
    const float* W_self    = (const float*)d_in[6];
    const float* W_intra   = (const float*)d_in[7];
    const float* W_inter   = (const float*)d_in[8];
    const int* event_sent  = (const int*)d_in[9];
    const int* event_start = (const int*)d_in[10];
    const int* event_len   = (const int*)d_in[11];
    const int* pair1       = (const int*)d_in[12];
    const int* pair2       = (const int*)d_in[13];
    const int* rel_type    = (const int*)d_in[14];
    const int* target      = (const int*)d_in[15];

    int E = in_sizes[9];    // 2000
    int P = in_sizes[12];   // 20000
    float* out = (float*)d_out;
    float* ws  = (float*)d_ws;

    // workspace layout (16B-aligned offsets). U aliases dead e_emb region.
    size_t o = 0;
    float* e_emb   = ws + o; o += (size_t)E * D_DIM;    // 2000x768 (dead after gemm_fused)
    float* A1      = ws + o; o += (size_t)E * H_DIM;
    float* A2      = ws + o; o += (size_t)E * H_DIM;
    float* X0      = ws + o; o += (size_t)E * NL_DIM;
    float* V       = ws + o; o += (size_t)E * H_DIM;
    float* X1      = ws + o; o += (size_t)E * NL_DIM;
    float* s_intra = ws + o; o += (size_t)E * NL_DIM;   // | contiguous zero region
    float* s_inter = ws + o; o += (size_t)E * NL_DIM;   // |
    float* c_intra = ws + o; o += (size_t)E;            // |
    float* c_inter = ws + o; o += (size_t)E;            // |
    int NBLK = (P + 15) / 16;                           // 1250
    float* ceb     = ws + o; o += (size_t)3 * NBLK;
    float* U       = e_emb;                             // alias: E*512 <= E*768

    // 1) event embeddings
    extract_kernel<<<E, 192, 0, stream>>>(sent_emb, event_sent, event_start, event_len, e_emb);

    // 2) big fused GEMM (one-wave blocks, all-async staging, direct write)
    dim3 gF(18, (E + GTM - 1) / GTM);                   // 18 x 32 = 576 one-wave blocks
    gemm_fused<<<gF, 64, 0, stream>>>(e_emb, W1, W_proj, A1, A2, X0, E);

    const float* W1k = W1 + (size_t)2 * D_DIM * H_DIM;  // rows 1536..1663
    dim3 gY(H_DIM / TN, (E + TM - 1) / TM);             // 8 x 32
    dim3 gU(NL_DIM / TN, (E + TM - 1) / TM);            // 2 x 32
    float* xcur = X0;
    float* xnext = X1;
    int zn4 = (E * NL_DIM * 2 + E * 2) / 4;             // s_intra..c_inter in float4s
    for (int it = 0; it < 3; ++it) {
        int last = (it == 2);
        gemm_y_uv<<<gY, 256, 0, stream>>>(xcur, W1k, A1, A2, b1, U, V,
                                          (float4*)s_intra, zn4, E);
        pair_kernel<<<NBLK, 256, 0, stream>>>(U, V, xcur, W2, b2,
                                              pair1, pair2, rel_type, target,
                                              s_intra, s_inter, c_intra, c_inter,
                                              ceb + (size_t)it * NBLK,
                                              last ? (out + 1) : nullptr, P, !last);
        if (!last) {
            gemm_update3<<<gU, 256, 0, stream>>>(xcur, s_intra, s_inter, c_intra, c_inter,
                                                 W_self, W_intra, W_inter, xnext, E);
            float* tmp = xcur; xcur = xnext; xnext = tmp;
        }
    }
    loss_kernel<<<1, 256, 0, stream>>>(ceb, NBLK, P, out);
}